// Round 1
// baseline (115.778 us; speedup 1.0000x reference)
//
#include <hip/hip_runtime.h>
#include <hip/hip_bf16.h>
#include <stdint.h>

typedef __attribute__((ext_vector_type(8))) short bf16x8;
typedef __attribute__((ext_vector_type(4))) float f32x4;

#define TWO_N 8192
#define NHALF 4096
#define DIM   128

// RNE f32 -> bf16 bits (inputs finite)
__device__ __forceinline__ unsigned int f2bf(float f) {
  unsigned int u = __float_as_uint(f);
  u += 0x7FFFu + ((u >> 16) & 1u);
  return u >> 16;
}

// ---------------- Kernel A: normalize rows of [zjs; zis] -> bf16 ----------------
__global__ __launch_bounds__(256) void norm_kernel(
    const float* __restrict__ zis, const float* __restrict__ zjs,
    unsigned int* __restrict__ rbf /* packed 2x bf16 per uint */) {
  const int wave = threadIdx.x >> 6;
  const int lane = threadIdx.x & 63;
  const int row = blockIdx.x * 4 + wave;
  const float* src = (row < NHALF) ? (zjs + (size_t)row * DIM)
                                   : (zis + (size_t)(row - NHALF) * DIM);
  float2 v = ((const float2*)src)[lane];
  float ss = v.x * v.x + v.y * v.y;
#pragma unroll
  for (int m = 1; m <= 32; m <<= 1) ss += __shfl_xor(ss, m);
  const float scale = 1.0f / fmaxf(sqrtf(ss), 1e-8f);
  const unsigned int lo = f2bf(v.x * scale);
  const unsigned int hi = f2bf(v.y * scale);
  rbf[(size_t)row * (DIM / 2) + lane] = lo | (hi << 16);
}

// async 16B global->LDS; LDS dest is wave-uniform-base + lane*16 (linear order)
#define GLL16(SRC, DST) __builtin_amdgcn_global_load_lds( \
    (__attribute__((address_space(1))) void*)(SRC),       \
    (__attribute__((address_space(3))) void*)(DST), 16, 0, 0)

// ---------------- Kernel B: fused sim-tile GEMM + sum-of-exp ----------------
// grid = 512: rb = bid>>3 (row tile of 128), cs = bid&7 (col chunk of 1024)
__global__ __launch_bounds__(256, 2) void simloss_kernel(
    char* __restrict__ rbytes,        // bf16 r matrix, row-major [8192][256B]
    float* __restrict__ pos,          // [8192] cosine sim with partner
    float* __restrict__ s_part) {     // [16][8192] partial sum-of-exp
  __shared__ char Ab[32768];
  __shared__ char Bb[32768];
  const int t = threadIdx.x;
  const int rb = blockIdx.x >> 3;
  const int cs = blockIdx.x & 7;
  const int RB = rb * 128;
  const int wave = t >> 6;
  const int lane = t & 63;
  const int wr = wave >> 1, wc = wave & 1;
  const int lrow = lane >> 4, lcol = lane & 15;

  // stage A tile rows [RB, RB+128); XOR-swizzle applied via source address
#pragma unroll
  for (int i = 0; i < 8; ++i) {
    const int L = (i * 256 + t) * 16;
    const int row = L >> 8;
    const int cb = L & 255;
    GLL16(rbytes + (size_t)(RB + row) * 256 + (cb ^ ((row & 7) << 4)), Ab + L);
  }

  bf16x8 a_reg[4][4];
  float srun[4][4];
#pragma unroll
  for (int m = 0; m < 4; ++m)
#pragma unroll
    for (int r = 0; r < 4; ++r) srun[m][r] = 0.0f;

  for (int ct = 0; ct < 8; ++ct) {
    const int CB = cs * 1024 + ct * 128;
#pragma unroll
    for (int i = 0; i < 8; ++i) {
      const int L = (i * 256 + t) * 16;
      const int row = L >> 8;
      const int cb = L & 255;
      GLL16(rbytes + (size_t)(CB + row) * 256 + (cb ^ ((row & 7) << 4)), Bb + L);
    }
    __syncthreads();  // compiler emits s_waitcnt vmcnt(0) before s_barrier

    if (ct == 0) {  // hoist A fragments into registers once
#pragma unroll
      for (int ks = 0; ks < 4; ++ks)
#pragma unroll
        for (int m = 0; m < 4; ++m) {
          const int row = wr * 64 + m * 16 + lcol;
          const int kb = ks * 64 + lrow * 16;
          a_reg[ks][m] = *(const bf16x8*)(Ab + row * 256 + (kb ^ ((row & 7) << 4)));
        }
    }

    f32x4 acc[4][4];
#pragma unroll
    for (int m = 0; m < 4; ++m)
#pragma unroll
      for (int n = 0; n < 4; ++n) acc[m][n] = (f32x4){0.f, 0.f, 0.f, 0.f};

#pragma unroll
    for (int ks = 0; ks < 4; ++ks) {
      bf16x8 bfr[4];
#pragma unroll
      for (int n = 0; n < 4; ++n) {
        const int row = wc * 64 + n * 16 + lcol;
        const int kb = ks * 64 + lrow * 16;
        bfr[n] = *(const bf16x8*)(Bb + row * 256 + (kb ^ ((row & 7) << 4)));
      }
#pragma unroll
      for (int m = 0; m < 4; ++m)
#pragma unroll
        for (int n = 0; n < 4; ++n)
          acc[m][n] = __builtin_amdgcn_mfma_f32_16x16x32_bf16(
              a_reg[ks][m], bfr[n], acc[m][n], 0, 0, 0);
    }

    // epilogue: z = 2*sim; accumulate exp(z) = exp2(sim * 2/ln2); mask diag; grab positive
#pragma unroll
    for (int m = 0; m < 4; ++m) {
      const int R0 = RB + wr * 64 + m * 16;
#pragma unroll
      for (int n = 0; n < 4; ++n) {
        const int C0 = CB + wc * 64 + n * 16;
        const bool hasDiag = (C0 == R0);            // wave-uniform
        const bool hasPartner = (C0 == (R0 ^ 4096)); // wave-uniform
#pragma unroll
        for (int r = 0; r < 4; ++r) {
          const float v = acc[m][n][r];
          float e = __builtin_amdgcn_exp2f(v * 2.8853900817779268f);
          const bool mine = (lcol == lrow * 4 + r);
          if (hasPartner && mine) pos[R0 + lrow * 4 + r] = v;
          if (hasDiag && mine) e = 0.0f;
          srun[m][r] += e;
        }
      }
    }
    __syncthreads();  // all waves done reading Bb before next stage
  }

  // butterfly-sum across the 16 lanes sharing each output row, store partials
#pragma unroll
  for (int m = 0; m < 4; ++m)
#pragma unroll
    for (int r = 0; r < 4; ++r) {
      float s = srun[m][r];
      s += __shfl_xor(s, 1);
      s += __shfl_xor(s, 2);
      s += __shfl_xor(s, 4);
      s += __shfl_xor(s, 8);
      if (lcol == 0)
        s_part[(size_t)(cs * 2 + wc) * TWO_N +
               (RB + wr * 64 + m * 16 + lrow * 4 + r)] = s;
    }
}

// ---------------- Kernel C: combine partials -> scalar loss ----------------
__global__ __launch_bounds__(1024) void reduce_kernel(
    const float* __restrict__ pos, const float* __restrict__ s_part,
    float* __restrict__ out) {
  const int t = threadIdx.x;
  float local = 0.0f;
#pragma unroll
  for (int i = 0; i < 8; ++i) {
    const int row = t + i * 1024;
    float s = 0.0f;
#pragma unroll
    for (int q = 0; q < 16; ++q) s += s_part[(size_t)q * TWO_N + row];
    local += __logf(s) - 2.0f * pos[row];
  }
#pragma unroll
  for (int m = 1; m <= 32; m <<= 1) local += __shfl_xor(local, m);
  __shared__ float wsum[16];
  if ((t & 63) == 0) wsum[t >> 6] = local;
  __syncthreads();
  if (t == 0) {
    float tot = 0.0f;
#pragma unroll
    for (int w = 0; w < 16; ++w) tot += wsum[w];
    out[0] = tot * (1.0f / TWO_N);
  }
}

extern "C" void kernel_launch(void* const* d_in, const int* in_sizes, int n_in,
                              void* d_out, int out_size, void* d_ws, size_t ws_size,
                              hipStream_t stream) {
  const float* zis = (const float*)d_in[0];
  const float* zjs = (const float*)d_in[1];
  char* ws = (char*)d_ws;
  unsigned int* rbf = (unsigned int*)ws;                         // 2 MB: bf16 r
  float* pos = (float*)(ws + 2u * 1024 * 1024);                  // 32 KB
  float* s_part = (float*)(ws + 2u * 1024 * 1024 + 32 * 1024);   // 512 KB

  norm_kernel<<<TWO_N / 4, 256, 0, stream>>>(zis, zjs, rbf);
  simloss_kernel<<<512, 256, 0, stream>>>((char*)rbf, pos, s_part);
  reduce_kernel<<<1, 1024, 0, stream>>>(pos, s_part, (float*)d_out);
}